// Round 15
// baseline (267.912 us; speedup 1.0000x reference)
//
#include <hip/hip_runtime.h>
#include <cstddef>

// Problem constants (B=4, S=2048, D=256, H=8, dh=32, d_ff=512), fp32 in/out.
constexpr int kB   = 4;
constexpr int kS   = 2048;
constexpr int kD   = 256;
constexpr int kH   = 8;
constexpr int kDH  = 32;
constexpr int kDFF = 512;
constexpr int kM   = kB * kS;   // 8192 token rows
constexpr float kEps = 1e-5f;
// 1/sqrt(32) * log2(e): scores pre-scaled so softmax uses exp2 directly.
constexpr float kScaleL2E = 0.17677669529663687f * 1.4426950408889634f;

typedef float f32x4  __attribute__((ext_vector_type(4)));
typedef short bf16x8 __attribute__((ext_vector_type(8)));
typedef unsigned short u16;
typedef unsigned int   u32;

__device__ inline u16 f2bf(float x) {
    union { float f; unsigned u; } c; c.f = x;
    const unsigned r = c.u + 0x7fffu + ((c.u >> 16) & 1u);
    return (u16)(r >> 16);
}

// pack two fp32 -> two bf16 (truncation) in ONE v_perm_b32.
__device__ inline u32 pk_trunc(float lo, float hi) {
    union { float f; u32 u; } a, b; a.f = lo; b.f = hi;
    return __builtin_amdgcn_perm(b.u, a.u, 0x07060302u);
}

// ---------------------------------------------------------------------------
// bf16 MFMA NT GEMM, M-pair fused K-loop, optional in-register LayerNorm on A.
// Block tile 128(M) x NT(N), 4 waves; wave w owns rows [m0+16w,+16) and
// [m0+64+16w,+16). W fp32 -> bf16 during linear coalesced LDS staging (once).
// If LNA: A is fp32; lane LayerNorms its 2 rows' 64-element quad-share into
// REGISTER fragments (pass1 sum -> shfl_xor quad-combine -> pass2 L1-warm
// reload + normalize + pack). Zero extra LDS (R7's failure mode avoided);
// K-loop consumes register A-frags. Else A is bf16 from global.
// LDS stride KTOT+4 (2-way bank aliasing = free).
// OUTMODE: 0 = fp32 (+RES), 1 = SiLU->bf16, 2 = QKV split:
//   Qb[bh][s][dh] (pre-scaled kScaleL2E), Kb[bh][s][dh],
//   Vp = quad-interleaved V: key so -> slot (vq=(so>>2)&3,
//   vj=(so&3)|(((so>>4)&1)<<2)), stored [bh][s/32][vq][dh][8].
// ---------------------------------------------------------------------------
template<int NT, int OUTMODE, bool RES, int KTOT, bool LNA>
__global__ __launch_bounds__(256)
void gemm_bf16(const void* __restrict__ Ain, const float* __restrict__ Wf,
               const float* __restrict__ bias,
               const float* __restrict__ lng, const float* __restrict__ lnb,
               const float* __restrict__ res,
               float* __restrict__ Cf, u16* __restrict__ Cb,
               u16* __restrict__ KbP, u16* __restrict__ VtP, int N)
{
    constexpr int BSTR = KTOT + 4;
    __shared__ u16 Bs[NT * BSTR];
    const int tid  = threadIdx.x;
    const int wave = tid >> 6;
    const int lane = tid & 63;
    const int quad = lane >> 4;
    const int l16  = lane & 15;
    const int m0 = blockIdx.x * 128;
    const int n0 = blockIdx.y * NT;

    // ---- stage W[n0:n0+NT, :] fp32 -> bf16, linear & coalesced (once) ----
    {
        constexpr int ITS = (NT * KTOT) / 1024;
        #pragma unroll
        for (int it = 0; it < ITS; ++it) {
            const int e   = it * 1024 + tid * 4;
            const int row = e / KTOT;
            const int col = e & (KTOT - 1);
            const float4 wv = *(const float4*)&Wf[(size_t)(n0 + row) * KTOT + col];
            *(ushort4*)&Bs[row * BSTR + col] = make_ushort4(
                f2bf(wv.x), f2bf(wv.y), f2bf(wv.z), f2bf(wv.w));
        }
    }

    // ---- LNA: LayerNorm this lane's rows into register fragments ----
    bf16x8 areg[2][LNA ? KTOT / 32 : 1];
    if constexpr (LNA) {
        static_assert(KTOT == 256, "LNA assumes K == D == 256");
        const float* Af = (const float*)Ain;
        #pragma unroll
        for (int mt = 0; mt < 2; ++mt) {
            const float* arow = &Af[(size_t)(m0 + mt * 64 + wave * 16 + l16) * kD];
            float s1 = 0.f, s2 = 0.f;
            #pragma unroll
            for (int t = 0; t < 8; ++t) {
                const float4 a0 = *(const float4*)&arow[t * 32 + quad * 8];
                const float4 a1 = *(const float4*)&arow[t * 32 + quad * 8 + 4];
                s1 += ((a0.x + a0.y) + (a0.z + a0.w))
                    + ((a1.x + a1.y) + (a1.z + a1.w));
                s2 = fmaf(a0.x, a0.x, s2); s2 = fmaf(a0.y, a0.y, s2);
                s2 = fmaf(a0.z, a0.z, s2); s2 = fmaf(a0.w, a0.w, s2);
                s2 = fmaf(a1.x, a1.x, s2); s2 = fmaf(a1.y, a1.y, s2);
                s2 = fmaf(a1.z, a1.z, s2); s2 = fmaf(a1.w, a1.w, s2);
            }
            s1 += __shfl_xor(s1, 16); s1 += __shfl_xor(s1, 32);
            s2 += __shfl_xor(s2, 16); s2 += __shfl_xor(s2, 32);
            const float mu   = s1 * (1.0f / kD);
            const float rsig = rsqrtf(s2 * (1.0f / kD) - mu * mu + kEps);
            #pragma unroll
            for (int t = 0; t < 8; ++t) {
                const float4 a0 = *(const float4*)&arow[t * 32 + quad * 8];
                const float4 a1 = *(const float4*)&arow[t * 32 + quad * 8 + 4];
                const float4 g0 = *(const float4*)&lng[t * 32 + quad * 8];
                const float4 g1 = *(const float4*)&lng[t * 32 + quad * 8 + 4];
                const float4 b0 = *(const float4*)&lnb[t * 32 + quad * 8];
                const float4 b1 = *(const float4*)&lnb[t * 32 + quad * 8 + 4];
                float e[8];
                e[0] = fmaf((a0.x - mu) * rsig, g0.x, b0.x);
                e[1] = fmaf((a0.y - mu) * rsig, g0.y, b0.y);
                e[2] = fmaf((a0.z - mu) * rsig, g0.z, b0.z);
                e[3] = fmaf((a0.w - mu) * rsig, g0.w, b0.w);
                e[4] = fmaf((a1.x - mu) * rsig, g1.x, b1.x);
                e[5] = fmaf((a1.y - mu) * rsig, g1.y, b1.y);
                e[6] = fmaf((a1.z - mu) * rsig, g1.z, b1.z);
                e[7] = fmaf((a1.w - mu) * rsig, g1.w, b1.w);
                union { u32 u[4]; bf16x8 v; } P;
                P.u[0] = pk_trunc(e[0], e[1]);
                P.u[1] = pk_trunc(e[2], e[3]);
                P.u[2] = pk_trunc(e[4], e[5]);
                P.u[3] = pk_trunc(e[6], e[7]);
                areg[mt][t] = P.v;
            }
        }
    }
    __syncthreads();

    f32x4 acc[2][NT / 16];
    #pragma unroll
    for (int mt = 0; mt < 2; ++mt)
        #pragma unroll
        for (int ni = 0; ni < NT / 16; ++ni) acc[mt][ni] = {0.f, 0.f, 0.f, 0.f};

    const u16* arow0 = LNA ? nullptr : &((const u16*)Ain)[(size_t)(m0 + wave * 16 + l16) * KTOT];
    const u16* arow1 = LNA ? nullptr : &((const u16*)Ain)[(size_t)(m0 + 64 + wave * 16 + l16) * KTOT];
    #pragma unroll 4
    for (int k0 = 0; k0 < KTOT; k0 += 32) {
        bf16x8 a0, a1;
        if constexpr (LNA) {
            a0 = areg[0][k0 / 32];
            a1 = areg[1][k0 / 32];
        } else {
            a0 = *(const bf16x8*)&arow0[k0 + quad * 8];
            a1 = *(const bf16x8*)&arow1[k0 + quad * 8];
        }
        #pragma unroll
        for (int ni = 0; ni < NT / 16; ++ni) {
            const bf16x8 bf = *(const bf16x8*)&Bs[(ni * 16 + l16) * BSTR + k0 + quad * 8];
            acc[0][ni] = __builtin_amdgcn_mfma_f32_16x16x32_bf16(a0, bf, acc[0][ni], 0, 0, 0);
            acc[1][ni] = __builtin_amdgcn_mfma_f32_16x16x32_bf16(a1, bf, acc[1][ni], 0, 0, 0);
        }
    }

    // ---- epilogue (both m-halves) ----
    #pragma unroll
    for (int mt = 0; mt < 2; ++mt) {
        #pragma unroll
        for (int ni = 0; ni < NT / 16; ++ni) {
            const float bias_v = bias[n0 + ni * 16 + l16];
            #pragma unroll
            for (int r = 0; r < 4; ++r) {
                const int m = m0 + mt * 64 + wave * 16 + quad * 4 + r;
                float v = acc[mt][ni][r] + bias_v;
                if (OUTMODE == 0) {
                    const int n = n0 + ni * 16 + l16;
                    if (RES) v += res[(size_t)m * N + n];
                    Cf[(size_t)m * N + n] = v;
                } else if (OUTMODE == 1) {
                    const int n = n0 + ni * 16 + l16;
                    v = v / (1.0f + __expf(-v));
                    Cb[(size_t)m * N + n] = f2bf(v);
                } else {
                    const int rgn = n0 >> 8;               // 0=Q 1=K 2=V
                    const int nl  = (n0 & 255) + ni * 16 + l16;
                    const int hh  = nl >> 5, dh = nl & 31;
                    const int bb  = m >> 11, s = m & (kS - 1);
                    const int bh  = bb * kH + hh;
                    if (rgn == 0)
                        Cb[((size_t)bh * kS + s) * kDH + dh] = f2bf(v * kScaleL2E);
                    else if (rgn == 1)
                        KbP[((size_t)bh * kS + s) * kDH + dh] = f2bf(v);
                    else {
                        // quad-interleave within 32-key block
                        const int so = s & 31;
                        const int vq = (so >> 2) & 3;
                        const int vj = (so & 3) | (((so >> 4) & 1) << 2);
                        VtP[(((size_t)bh * (kS / 32) + (s >> 5)) * 4 + vq) * 256
                            + dh * 8 + vj] = f2bf(v);
                    }
                }
            }
        }
    }
}

// ---------------------------------------------------------------------------
// MFMA flash attention (R14: in-register P, raw v_exp_f32, zero main-loop
// LDS). S^T = mfma(A=K_frag, B=Q_frag); lane packs its query's exp2'd scores
// straight into PV A-frags (key permutation matched by quad-interleaved V).
// No-max softmax; LDS only for the additive half-combine.
// Block = 4 waves: (qsub=wave>>1)*32 queries x (half=wave&1)*1024 keys.
// Grid (kS/64=32, 8, 4) = 1024 blocks.
// ---------------------------------------------------------------------------
__global__ __launch_bounds__(256)
void attn_kernel(const u16* __restrict__ Qb, const u16* __restrict__ Kb,
                 const u16* __restrict__ Vp, u16* __restrict__ ctx)
{
    __shared__ float cbuf[2][32 * 33];     // combine buffer only (8448 B)
    const int tid  = threadIdx.x;
    const int wave = tid >> 6;
    const int lane = tid & 63;
    const int quad = lane >> 4;
    const int l16  = lane & 15;
    const int h = blockIdx.y;
    const int b = blockIdx.z;
    const int bh = b * kH + h;
    const int qsub = wave >> 1;
    const int half = wave & 1;
    const int q0 = blockIdx.x * 64 + qsub * 32;

    bf16x8 aq[2];
    aq[0] = *(const bf16x8*)&Qb[((size_t)bh * kS + q0 + l16) * kDH + quad * 8];
    aq[1] = *(const bf16x8*)&Qb[((size_t)bh * kS + q0 + 16 + l16) * kDH + quad * 8];

    const u16* Kbase = Kb + (size_t)bh * kS * kDH;
    const u16* Vbase = Vp + (size_t)bh * (kS * 32);

    f32x4 O[2][2] = {};
    float lp[2] = {0.f, 0.f};
    const f32x4 zz = {0.f, 0.f, 0.f, 0.f};

    const int kbeg = half * (kS / 2);
    #pragma unroll 1
    for (int kt = kbeg; kt < kbeg + kS / 2; kt += 64) {
        bf16x8 kf[4];
        #pragma unroll
        for (int kg = 0; kg < 4; ++kg)
            kf[kg] = *(const bf16x8*)
                &Kbase[(size_t)(kt + kg * 16 + l16) * kDH + quad * 8];
        bf16x8 vf[2][2];
        #pragma unroll
        for (int ks = 0; ks < 2; ++ks)
            #pragma unroll
            for (int nf = 0; nf < 2; ++nf)
                vf[ks][nf] = *(const bf16x8*)
                    &Vbase[(size_t)(((kt >> 5) + ks) * 4 + quad) * 1024
                           + (nf * 16 + l16) * 8];

        #pragma unroll
        for (int qb = 0; qb < 2; ++qb) {
            f32x4 S[4];
            #pragma unroll
            for (int kg = 0; kg < 4; ++kg)
                S[kg] = __builtin_amdgcn_mfma_f32_16x16x32_bf16(kf[kg], aq[qb], zz, 0, 0, 0);

            float e0[8], e1[8];
            #pragma unroll
            for (int r = 0; r < 4; ++r) {
                e0[r]     = __builtin_amdgcn_exp2f(S[0][r]);
                e0[4 + r] = __builtin_amdgcn_exp2f(S[1][r]);
                e1[r]     = __builtin_amdgcn_exp2f(S[2][r]);
                e1[4 + r] = __builtin_amdgcn_exp2f(S[3][r]);
            }
            lp[qb] += ((e0[0] + e0[1]) + (e0[2] + e0[3]))
                    + ((e0[4] + e0[5]) + (e0[6] + e0[7]))
                    + ((e1[0] + e1[1]) + (e1[2] + e1[3]))
                    + ((e1[4] + e1[5]) + (e1[6] + e1[7]));
            union { u32 u[4]; bf16x8 v; } pA0, pA1;
            pA0.u[0] = pk_trunc(e0[0], e0[1]);
            pA0.u[1] = pk_trunc(e0[2], e0[3]);
            pA0.u[2] = pk_trunc(e0[4], e0[5]);
            pA0.u[3] = pk_trunc(e0[6], e0[7]);
            pA1.u[0] = pk_trunc(e1[0], e1[1]);
            pA1.u[1] = pk_trunc(e1[2], e1[3]);
            pA1.u[2] = pk_trunc(e1[4], e1[5]);
            pA1.u[3] = pk_trunc(e1[6], e1[7]);

            O[qb][0] = __builtin_amdgcn_mfma_f32_16x16x32_bf16(pA0.v, vf[0][0], O[qb][0], 0, 0, 0);
            O[qb][1] = __builtin_amdgcn_mfma_f32_16x16x32_bf16(pA0.v, vf[0][1], O[qb][1], 0, 0, 0);
            O[qb][0] = __builtin_amdgcn_mfma_f32_16x16x32_bf16(pA1.v, vf[1][0], O[qb][0], 0, 0, 0);
            O[qb][1] = __builtin_amdgcn_mfma_f32_16x16x32_bf16(pA1.v, vf[1][1], O[qb][1], 0, 0, 0);
        }
    }

    #pragma unroll
    for (int qb = 0; qb < 2; ++qb) {
        lp[qb] += __shfl_xor(lp[qb], 16);
        lp[qb] += __shfl_xor(lp[qb], 32);
    }

    float* cb = cbuf[qsub];
    if (half == 1) {
        #pragma unroll
        for (int qb = 0; qb < 2; ++qb)
            #pragma unroll
            for (int r = 0; r < 4; ++r) {
                const int row = qb * 16 + quad * 4 + r;
                cb[row * 33 + l16]      = O[qb][0][r];
                cb[row * 33 + 16 + l16] = O[qb][1][r];
                if (l16 == 0)
                    cb[row * 33 + 32] = __shfl(lp[qb], quad * 4 + r);
            }
    }
    __syncthreads();
    if (half == 0) {
        #pragma unroll
        for (int qb = 0; qb < 2; ++qb)
            #pragma unroll
            for (int r = 0; r < 4; ++r) {
                const int row = qb * 16 + quad * 4 + r;
                const float lq  = __shfl(lp[qb], quad * 4 + r) + cb[row * 33 + 32];
                const float inv = 1.0f / lq;
                const float o0 = O[qb][0][r] + cb[row * 33 + l16];
                const float o1 = O[qb][1][r] + cb[row * 33 + 16 + l16];
                const int q = q0 + row;
                u16* crow = ctx + ((size_t)(b * kS + q)) * kD + h * kDH;
                crow[l16]      = f2bf(o0 * inv);
                crow[16 + l16] = f2bf(o1 * inv);
            }
    }
}

// ---------------------------------------------------------------------------
// 5 dispatches: qkv(+LN1) -> attn -> proj(+res) -> ffn1(+LN2+SiLU) ->
// ffn2(+res). Workspace (bytes):
//   [ 0M, 4M)  Qb   (bf16)  -- [0,8M) reused as h after attn
//   [ 4M, 8M)  Kb   (bf16)
//   [ 8M,12M)  Vp   (bf16, quad-interleaved)
//   [12M,16M)  ctx  (bf16)
// ---------------------------------------------------------------------------
extern "C" void kernel_launch(void* const* d_in, const int* in_sizes, int n_in,
                              void* d_out, int out_size, void* d_ws, size_t ws_size,
                              hipStream_t stream)
{
    const float* x      = (const float*)d_in[0];
    const float* ln1_g  = (const float*)d_in[1];
    const float* ln1_b  = (const float*)d_in[2];
    const float* w_qkv  = (const float*)d_in[3];
    const float* b_qkv  = (const float*)d_in[4];
    const float* w_proj = (const float*)d_in[5];
    const float* b_proj = (const float*)d_in[6];
    const float* ln2_g  = (const float*)d_in[7];
    const float* ln2_b  = (const float*)d_in[8];
    const float* w1     = (const float*)d_in[9];
    const float* b1     = (const float*)d_in[10];
    const float* w2     = (const float*)d_in[11];
    const float* b2     = (const float*)d_in[12];
    float* out = (float*)d_out;

    char* ws = (char*)d_ws;
    u16* Qb  = (u16*)ws;
    u16* Kb  = (u16*)(ws + ((size_t)4  << 20));
    u16* Vp  = (u16*)(ws + ((size_t)8  << 20));
    u16* ctx = (u16*)(ws + ((size_t)12 << 20));
    u16* h   = (u16*)ws;                     // aliases Qb/Kb (dead after attn)

    const dim3 blk(256);

    // 1) Qb/Kb/Vp = bf16(LN1(x) @ w_qkv.T + b_qkv), Q pre-scaled, V interleaved
    gemm_bf16<64, 2, false, 256, true><<<dim3(kM / 128, 12), blk, 0, stream>>>(
        x, w_qkv, b_qkv, ln1_g, ln1_b, nullptr,
        nullptr, Qb, Kb, Vp, 0);
    // 2) ctx = attention (bf16 out), in-register P
    attn_kernel<<<dim3(kS / 64, kH, kB), blk, 0, stream>>>(Qb, Kb, Vp, ctx);
    // 3) out = x + ctx @ w_proj.T + b_proj   (fp32)
    gemm_bf16<32, 0, true, 256, false><<<dim3(kM / 128, kD / 32), blk, 0, stream>>>(
        ctx, w_proj, b_proj, nullptr, nullptr, x,
        out, nullptr, nullptr, nullptr, kD);
    // 4) h = bf16(silu(LN2(out) @ w1.T + b1))
    gemm_bf16<64, 1, false, 256, true><<<dim3(kM / 128, kDFF / 64), blk, 0, stream>>>(
        out, w1, b1, ln2_g, ln2_b, nullptr,
        nullptr, h, nullptr, nullptr, kDFF);
    // 5) out = out + h @ w2.T + b2   (fp32, K=512)
    gemm_bf16<32, 0, true, 512, false><<<dim3(kM / 128, kD / 32), blk, 0, stream>>>(
        h, w2, b2, nullptr, nullptr, out,
        out, nullptr, nullptr, nullptr, kD);
}

// Round 16
// 216.278 us; speedup vs baseline: 1.2387x; 1.2387x over previous
//
#include <hip/hip_runtime.h>
#include <cstddef>

// Problem constants (B=4, S=2048, D=256, H=8, dh=32, d_ff=512), fp32 in/out.
constexpr int kB   = 4;
constexpr int kS   = 2048;
constexpr int kD   = 256;
constexpr int kH   = 8;
constexpr int kDH  = 32;
constexpr int kDFF = 512;
constexpr int kM   = kB * kS;   // 8192 token rows
constexpr float kEps = 1e-5f;
// 1/sqrt(32) * log2(e): scores pre-scaled so softmax uses exp2 directly.
constexpr float kScaleL2E = 0.17677669529663687f * 1.4426950408889634f;

typedef float f32x4  __attribute__((ext_vector_type(4)));
typedef short bf16x8 __attribute__((ext_vector_type(8)));
typedef unsigned short u16;
typedef unsigned int   u32;

__device__ inline u16 f2bf(float x) {
    union { float f; unsigned u; } c; c.f = x;
    const unsigned r = c.u + 0x7fffu + ((c.u >> 16) & 1u);
    return (u16)(r >> 16);
}

// pack two fp32 -> two bf16 (truncation) in ONE v_perm_b32.
__device__ inline u32 pk_trunc(float lo, float hi) {
    union { float f; u32 u; } a, b; a.f = lo; b.f = hi;
    return __builtin_amdgcn_perm(b.u, a.u, 0x07060302u);
}

// ---------------------------------------------------------------------------
// LayerNorm: 4 rows/block, one wave per row, 4 floats/lane, pure-shuffle
// reduction. bf16 out. (R6/R14-proven.)
// ---------------------------------------------------------------------------
__global__ __launch_bounds__(256)
void ln_kernel(const float* __restrict__ x, const float* __restrict__ g,
               const float* __restrict__ b, u16* __restrict__ y)
{
    const int wave = threadIdx.x >> 6;
    const int lane = threadIdx.x & 63;
    const int row  = blockIdx.x * 4 + wave;
    const float4 v = *(const float4*)&x[(size_t)row * kD + lane * 4];
    float s1 = (v.x + v.y) + (v.z + v.w);
    float s2 = (v.x * v.x + v.y * v.y) + (v.z * v.z + v.w * v.w);
    #pragma unroll
    for (int off = 1; off < 64; off <<= 1) {
        s1 += __shfl_xor(s1, off);
        s2 += __shfl_xor(s2, off);
    }
    const float mu  = s1 * (1.0f / kD);
    const float var = s2 * (1.0f / kD) - mu * mu;
    const float inv = rsqrtf(var + kEps);
    const float4 g4 = *(const float4*)&g[lane * 4];
    const float4 b4 = *(const float4*)&b[lane * 4];
    *(ushort4*)&y[(size_t)row * kD + lane * 4] = make_ushort4(
        f2bf((v.x - mu) * inv * g4.x + b4.x),
        f2bf((v.y - mu) * inv * g4.y + b4.y),
        f2bf((v.z - mu) * inv * g4.z + b4.z),
        f2bf((v.w - mu) * inv * g4.w + b4.w));
}

// ---------------------------------------------------------------------------
// bf16 MFMA NT GEMM v16: REGISTER-B, ZERO LDS, zero barriers.
// Rationale: the LDS-staged K-loop was LDS-pipe-bound ~2.5x (per wave per
// k-step: 4 ds_read_b128 on the single per-CU LDS pipe vs 8 MFMAs on 4 SIMD
// pipes). B-fragments are wave-invariant; at NT=32 a 256-K chunk of B is
// only 16 bf16x8 = 64 VGPRs -> hold B in registers, loaded straight from
// global fp32 W (RNE cast, once per block, L2-broadcast across blocks).
// A-frags load straight from global (each A byte read once per block).
// Block tile 128(M) x 32(N): 4 waves, wave w owns rows [m0+16w,+16) and
// [m0+64+16w,+16); per k-step = 2 A loads + 4 MFMAs, all from registers/VMEM.
// KTOT=512 processes B in two 256-chunks (B-regs reloaded between).
// OUTMODE: 0 = fp32 (+RES), 1 = SiLU->bf16, 2 = QKV split:
//   Qb[bh][s][dh] (pre-scaled kScaleL2E), Kb[bh][s][dh],
//   Vp = quad-interleaved V: key so -> slot (vq=(so>>2)&3,
//   vj=(so&3)|(((so>>4)&1)<<2)), stored [bh][s/32][vq][dh][8].
// ---------------------------------------------------------------------------
template<int OUTMODE, bool RES, int KTOT>
__global__ __launch_bounds__(256)
void gemm_bf16(const u16* __restrict__ A, const float* __restrict__ Wf,
               const float* __restrict__ bias, const float* __restrict__ res,
               float* __restrict__ Cf, u16* __restrict__ Cb,
               u16* __restrict__ KbP, u16* __restrict__ VtP, int N)
{
    const int tid  = threadIdx.x;
    const int wave = tid >> 6;
    const int lane = tid & 63;
    const int quad = lane >> 4;
    const int l16  = lane & 15;
    const int m0 = blockIdx.x * 128;
    const int n0 = blockIdx.y * 32;

    f32x4 acc[2][2] = {};   // [m-half][ni]

    const u16* arow0 = &A[(size_t)(m0 + wave * 16 + l16) * KTOT];
    const u16* arow1 = &A[(size_t)(m0 + 64 + wave * 16 + l16) * KTOT];

    #pragma unroll
    for (int kc = 0; kc < KTOT; kc += 256) {
        // ---- B chunk -> registers: lane (quad,l16) needs
        //      W[n0+ni*16+l16][kc+t*32+quad*8 .. +8], RNE-cast to bf16 ----
        bf16x8 breg[2][8];
        #pragma unroll
        for (int ni = 0; ni < 2; ++ni) {
            const float* wrow = &Wf[(size_t)(n0 + ni * 16 + l16) * KTOT + kc + quad * 8];
            #pragma unroll
            for (int t = 0; t < 8; ++t) {
                const float4 w0 = *(const float4*)&wrow[t * 32];
                const float4 w1 = *(const float4*)&wrow[t * 32 + 4];
                union { ushort4 s[2]; bf16x8 v; } P;
                P.s[0] = make_ushort4(f2bf(w0.x), f2bf(w0.y), f2bf(w0.z), f2bf(w0.w));
                P.s[1] = make_ushort4(f2bf(w1.x), f2bf(w1.y), f2bf(w1.z), f2bf(w1.w));
                breg[ni][t] = P.v;
            }
        }
        // ---- K-loop: pure VMEM + MFMA ----
        #pragma unroll
        for (int t = 0; t < 8; ++t) {
            const int k0 = kc + t * 32;
            const bf16x8 a0 = *(const bf16x8*)&arow0[k0 + quad * 8];
            const bf16x8 a1 = *(const bf16x8*)&arow1[k0 + quad * 8];
            acc[0][0] = __builtin_amdgcn_mfma_f32_16x16x32_bf16(a0, breg[0][t], acc[0][0], 0, 0, 0);
            acc[1][0] = __builtin_amdgcn_mfma_f32_16x16x32_bf16(a1, breg[0][t], acc[1][0], 0, 0, 0);
            acc[0][1] = __builtin_amdgcn_mfma_f32_16x16x32_bf16(a0, breg[1][t], acc[0][1], 0, 0, 0);
            acc[1][1] = __builtin_amdgcn_mfma_f32_16x16x32_bf16(a1, breg[1][t], acc[1][1], 0, 0, 0);
        }
    }

    // ---- epilogue (both m-halves) ----
    #pragma unroll
    for (int mt = 0; mt < 2; ++mt) {
        #pragma unroll
        for (int ni = 0; ni < 2; ++ni) {
            const float bias_v = bias[n0 + ni * 16 + l16];
            #pragma unroll
            for (int r = 0; r < 4; ++r) {
                const int m = m0 + mt * 64 + wave * 16 + quad * 4 + r;
                float v = acc[mt][ni][r] + bias_v;
                if (OUTMODE == 0) {
                    const int n = n0 + ni * 16 + l16;
                    if (RES) v += res[(size_t)m * N + n];
                    Cf[(size_t)m * N + n] = v;
                } else if (OUTMODE == 1) {
                    const int n = n0 + ni * 16 + l16;
                    v = v / (1.0f + __expf(-v));
                    Cb[(size_t)m * N + n] = f2bf(v);
                } else {
                    const int rgn = n0 >> 8;               // 0=Q 1=K 2=V
                    const int nl  = (n0 & 255) + ni * 16 + l16;
                    const int hh  = nl >> 5, dh = nl & 31;
                    const int bb  = m >> 11, s = m & (kS - 1);
                    const int bh  = bb * kH + hh;
                    if (rgn == 0)
                        Cb[((size_t)bh * kS + s) * kDH + dh] = f2bf(v * kScaleL2E);
                    else if (rgn == 1)
                        KbP[((size_t)bh * kS + s) * kDH + dh] = f2bf(v);
                    else {
                        // quad-interleave within 32-key block
                        const int so = s & 31;
                        const int vq = (so >> 2) & 3;
                        const int vj = (so & 3) | (((so >> 4) & 1) << 2);
                        VtP[(((size_t)bh * (kS / 32) + (s >> 5)) * 4 + vq) * 256
                            + dh * 8 + vj] = f2bf(v);
                    }
                }
            }
        }
    }
}

// ---------------------------------------------------------------------------
// MFMA flash attention (R14-proven, byte-identical): in-register P, raw
// v_exp_f32, zero main-loop LDS. S^T = mfma(A=K_frag, B=Q_frag); lane packs
// its query's exp2'd scores straight into PV A-frags (key permutation
// matched by the quad-interleaved V layout). No-max softmax; LDS only for
// the additive half-combine.
// Block = 4 waves: (qsub=wave>>1)*32 queries x (half=wave&1)*1024 keys.
// Grid (kS/64=32, 8, 4) = 1024 blocks.
// ---------------------------------------------------------------------------
__global__ __launch_bounds__(256)
void attn_kernel(const u16* __restrict__ Qb, const u16* __restrict__ Kb,
                 const u16* __restrict__ Vp, u16* __restrict__ ctx)
{
    __shared__ float cbuf[2][32 * 33];     // combine buffer only (8448 B)
    const int tid  = threadIdx.x;
    const int wave = tid >> 6;
    const int lane = tid & 63;
    const int quad = lane >> 4;
    const int l16  = lane & 15;
    const int h = blockIdx.y;
    const int b = blockIdx.z;
    const int bh = b * kH + h;
    const int qsub = wave >> 1;
    const int half = wave & 1;
    const int q0 = blockIdx.x * 64 + qsub * 32;

    bf16x8 aq[2];
    aq[0] = *(const bf16x8*)&Qb[((size_t)bh * kS + q0 + l16) * kDH + quad * 8];
    aq[1] = *(const bf16x8*)&Qb[((size_t)bh * kS + q0 + 16 + l16) * kDH + quad * 8];

    const u16* Kbase = Kb + (size_t)bh * kS * kDH;
    const u16* Vbase = Vp + (size_t)bh * (kS * 32);

    f32x4 O[2][2] = {};
    float lp[2] = {0.f, 0.f};
    const f32x4 zz = {0.f, 0.f, 0.f, 0.f};

    const int kbeg = half * (kS / 2);
    #pragma unroll 1
    for (int kt = kbeg; kt < kbeg + kS / 2; kt += 64) {
        bf16x8 kf[4];
        #pragma unroll
        for (int kg = 0; kg < 4; ++kg)
            kf[kg] = *(const bf16x8*)
                &Kbase[(size_t)(kt + kg * 16 + l16) * kDH + quad * 8];
        bf16x8 vf[2][2];
        #pragma unroll
        for (int ks = 0; ks < 2; ++ks)
            #pragma unroll
            for (int nf = 0; nf < 2; ++nf)
                vf[ks][nf] = *(const bf16x8*)
                    &Vbase[(size_t)(((kt >> 5) + ks) * 4 + quad) * 1024
                           + (nf * 16 + l16) * 8];

        #pragma unroll
        for (int qb = 0; qb < 2; ++qb) {
            f32x4 S[4];
            #pragma unroll
            for (int kg = 0; kg < 4; ++kg)
                S[kg] = __builtin_amdgcn_mfma_f32_16x16x32_bf16(kf[kg], aq[qb], zz, 0, 0, 0);

            float e0[8], e1[8];
            #pragma unroll
            for (int r = 0; r < 4; ++r) {
                e0[r]     = __builtin_amdgcn_exp2f(S[0][r]);
                e0[4 + r] = __builtin_amdgcn_exp2f(S[1][r]);
                e1[r]     = __builtin_amdgcn_exp2f(S[2][r]);
                e1[4 + r] = __builtin_amdgcn_exp2f(S[3][r]);
            }
            lp[qb] += ((e0[0] + e0[1]) + (e0[2] + e0[3]))
                    + ((e0[4] + e0[5]) + (e0[6] + e0[7]))
                    + ((e1[0] + e1[1]) + (e1[2] + e1[3]))
                    + ((e1[4] + e1[5]) + (e1[6] + e1[7]));
            union { u32 u[4]; bf16x8 v; } pA0, pA1;
            pA0.u[0] = pk_trunc(e0[0], e0[1]);
            pA0.u[1] = pk_trunc(e0[2], e0[3]);
            pA0.u[2] = pk_trunc(e0[4], e0[5]);
            pA0.u[3] = pk_trunc(e0[6], e0[7]);
            pA1.u[0] = pk_trunc(e1[0], e1[1]);
            pA1.u[1] = pk_trunc(e1[2], e1[3]);
            pA1.u[2] = pk_trunc(e1[4], e1[5]);
            pA1.u[3] = pk_trunc(e1[6], e1[7]);

            O[qb][0] = __builtin_amdgcn_mfma_f32_16x16x32_bf16(pA0.v, vf[0][0], O[qb][0], 0, 0, 0);
            O[qb][1] = __builtin_amdgcn_mfma_f32_16x16x32_bf16(pA0.v, vf[0][1], O[qb][1], 0, 0, 0);
            O[qb][0] = __builtin_amdgcn_mfma_f32_16x16x32_bf16(pA1.v, vf[1][0], O[qb][0], 0, 0, 0);
            O[qb][1] = __builtin_amdgcn_mfma_f32_16x16x32_bf16(pA1.v, vf[1][1], O[qb][1], 0, 0, 0);
        }
    }

    #pragma unroll
    for (int qb = 0; qb < 2; ++qb) {
        lp[qb] += __shfl_xor(lp[qb], 16);
        lp[qb] += __shfl_xor(lp[qb], 32);
    }

    float* cb = cbuf[qsub];
    if (half == 1) {
        #pragma unroll
        for (int qb = 0; qb < 2; ++qb)
            #pragma unroll
            for (int r = 0; r < 4; ++r) {
                const int row = qb * 16 + quad * 4 + r;
                cb[row * 33 + l16]      = O[qb][0][r];
                cb[row * 33 + 16 + l16] = O[qb][1][r];
                if (l16 == 0)
                    cb[row * 33 + 32] = __shfl(lp[qb], quad * 4 + r);
            }
    }
    __syncthreads();
    if (half == 0) {
        #pragma unroll
        for (int qb = 0; qb < 2; ++qb)
            #pragma unroll
            for (int r = 0; r < 4; ++r) {
                const int row = qb * 16 + quad * 4 + r;
                const float lq  = __shfl(lp[qb], quad * 4 + r) + cb[row * 33 + 32];
                const float inv = 1.0f / lq;
                const float o0 = O[qb][0][r] + cb[row * 33 + l16];
                const float o1 = O[qb][1][r] + cb[row * 33 + 16 + l16];
                const int q = q0 + row;
                u16* crow = ctx + ((size_t)(b * kS + q)) * kD + h * kDH;
                crow[l16]      = f2bf(o0 * inv);
                crow[16 + l16] = f2bf(o1 * inv);
            }
    }
}

// ---------------------------------------------------------------------------
// 7 dispatches: ln1 -> qkv -> attn -> proj(+res) -> ln2 -> ffn1(SiLU) ->
// ffn2(+res). Workspace (bytes):
//   [ 0M, 4M)  Qb   (bf16)  -- [0,8M) reused as h after attn
//   [ 4M, 8M)  Kb   (bf16)
//   [ 8M,12M)  Vp   (bf16, quad-interleaved)
//   [12M,16M)  ctx  (bf16)
//   [16M,20M)  y    (bf16, LN1 then LN2)
// ---------------------------------------------------------------------------
extern "C" void kernel_launch(void* const* d_in, const int* in_sizes, int n_in,
                              void* d_out, int out_size, void* d_ws, size_t ws_size,
                              hipStream_t stream)
{
    const float* x      = (const float*)d_in[0];
    const float* ln1_g  = (const float*)d_in[1];
    const float* ln1_b  = (const float*)d_in[2];
    const float* w_qkv  = (const float*)d_in[3];
    const float* b_qkv  = (const float*)d_in[4];
    const float* w_proj = (const float*)d_in[5];
    const float* b_proj = (const float*)d_in[6];
    const float* ln2_g  = (const float*)d_in[7];
    const float* ln2_b  = (const float*)d_in[8];
    const float* w1     = (const float*)d_in[9];
    const float* b1     = (const float*)d_in[10];
    const float* w2     = (const float*)d_in[11];
    const float* b2     = (const float*)d_in[12];
    float* out = (float*)d_out;

    char* ws = (char*)d_ws;
    u16* Qb  = (u16*)ws;
    u16* Kb  = (u16*)(ws + ((size_t)4  << 20));
    u16* Vp  = (u16*)(ws + ((size_t)8  << 20));
    u16* ctx = (u16*)(ws + ((size_t)12 << 20));
    u16* y   = (u16*)(ws + ((size_t)16 << 20));
    u16* h   = (u16*)ws;                     // aliases Qb/Kb (dead after attn)

    const dim3 blk(256);

    // 1) y = bf16(LN1(x))
    ln_kernel<<<dim3(kM / 4), blk, 0, stream>>>(x, ln1_g, ln1_b, y);
    // 2) Qb/Kb/Vp = bf16(y @ w_qkv.T + b_qkv), Q pre-scaled, V interleaved
    gemm_bf16<2, false, 256><<<dim3(kM / 128, 24), blk, 0, stream>>>(
        y, w_qkv, b_qkv, nullptr, nullptr, Qb, Kb, Vp, 0);
    // 3) ctx = attention (bf16 out), in-register P
    attn_kernel<<<dim3(kS / 64, kH, kB), blk, 0, stream>>>(Qb, Kb, Vp, ctx);
    // 4) out = x + ctx @ w_proj.T + b_proj   (fp32)
    gemm_bf16<0, true, 256><<<dim3(kM / 128, kD / 32), blk, 0, stream>>>(
        ctx, w_proj, b_proj, x, out, nullptr, nullptr, nullptr, kD);
    // 5) y = bf16(LN2(out))
    ln_kernel<<<dim3(kM / 4), blk, 0, stream>>>(out, ln2_g, ln2_b, y);
    // 6) h = bf16(silu(y @ w1.T + b1))
    gemm_bf16<1, false, 256><<<dim3(kM / 128, kDFF / 32), blk, 0, stream>>>(
        y, w1, b1, nullptr, nullptr, h, nullptr, nullptr, kDFF);
    // 7) out = out + h @ w2.T + b2   (fp32, K=512, B in two chunks)
    gemm_bf16<0, true, 512><<<dim3(kM / 128, kD / 32), blk, 0, stream>>>(
        h, w2, b2, out, out, nullptr, nullptr, nullptr, kD);
}

// Round 17
// 184.221 us; speedup vs baseline: 1.4543x; 1.1740x over previous
//
#include <hip/hip_runtime.h>
#include <cstddef>

// Problem constants (B=4, S=2048, D=256, H=8, dh=32, d_ff=512), fp32 in/out.
constexpr int kB   = 4;
constexpr int kS   = 2048;
constexpr int kD   = 256;
constexpr int kH   = 8;
constexpr int kDH  = 32;
constexpr int kDFF = 512;
constexpr int kM   = kB * kS;   // 8192 token rows
constexpr float kEps = 1e-5f;
// 1/sqrt(32) * log2(e): scores pre-scaled so softmax uses exp2 directly.
constexpr float kScaleL2E = 0.17677669529663687f * 1.4426950408889634f;

typedef float f32x4  __attribute__((ext_vector_type(4)));
typedef short bf16x8 __attribute__((ext_vector_type(8)));
typedef unsigned short u16;
typedef unsigned int   u32;

__device__ inline u16 f2bf(float x) {
    union { float f; unsigned u; } c; c.f = x;
    const unsigned r = c.u + 0x7fffu + ((c.u >> 16) & 1u);
    return (u16)(r >> 16);
}

// pack two fp32 -> two bf16 (truncation) in ONE v_perm_b32.
__device__ inline u32 pk_trunc(float lo, float hi) {
    union { float f; u32 u; } a, b; a.f = lo; b.f = hi;
    return __builtin_amdgcn_perm(b.u, a.u, 0x07060302u);
}

// ---------------------------------------------------------------------------
// LayerNorm: 4 rows/block, one wave per row, 4 floats/lane, pure-shuffle
// reduction. bf16 out. (R6/R14-proven.)
// ---------------------------------------------------------------------------
__global__ __launch_bounds__(256)
void ln_kernel(const float* __restrict__ x, const float* __restrict__ g,
               const float* __restrict__ b, u16* __restrict__ y)
{
    const int wave = threadIdx.x >> 6;
    const int lane = threadIdx.x & 63;
    const int row  = blockIdx.x * 4 + wave;
    const float4 v = *(const float4*)&x[(size_t)row * kD + lane * 4];
    float s1 = (v.x + v.y) + (v.z + v.w);
    float s2 = (v.x * v.x + v.y * v.y) + (v.z * v.z + v.w * v.w);
    #pragma unroll
    for (int off = 1; off < 64; off <<= 1) {
        s1 += __shfl_xor(s1, off);
        s2 += __shfl_xor(s2, off);
    }
    const float mu  = s1 * (1.0f / kD);
    const float var = s2 * (1.0f / kD) - mu * mu;
    const float inv = rsqrtf(var + kEps);
    const float4 g4 = *(const float4*)&g[lane * 4];
    const float4 b4 = *(const float4*)&b[lane * 4];
    *(ushort4*)&y[(size_t)row * kD + lane * 4] = make_ushort4(
        f2bf((v.x - mu) * inv * g4.x + b4.x),
        f2bf((v.y - mu) * inv * g4.y + b4.y),
        f2bf((v.z - mu) * inv * g4.z + b4.z),
        f2bf((v.w - mu) * inv * g4.w + b4.w));
}

// ---------------------------------------------------------------------------
// bf16 MFMA NT GEMM v17: M-QUAD fused K-loop (LDS-staged B, MFMA-bound).
// Block tile 256(M) x 32(N), 4 waves; wave w owns rows m0+mt*64+16w (+16)
// for mt=0..3. Per wave per k-step: 2 ds_read_b128 (~24 cyc shared LDS pipe)
// feed 8 MFMAs (~155 SIMD-cyc) -> MFMA-bound (R14 at NT=32 was 24:77,
// LDS-bound). W fp32 -> bf16 during linear coalesced LDS staging (once).
// LDS stride KTOT+4 (2-way bank aliasing = free).
// OUTMODE: 0 = fp32 (+RES), 1 = SiLU->bf16, 2 = QKV split:
//   Qb[bh][s][dh] (pre-scaled kScaleL2E), Kb[bh][s][dh],
//   Vp = quad-interleaved V: key so -> slot (vq=(so>>2)&3,
//   vj=(so&3)|(((so>>4)&1)<<2)), stored [bh][s/32][vq][dh][8].
// ---------------------------------------------------------------------------
template<int OUTMODE, bool RES, int KTOT>
__global__ __launch_bounds__(256)
void gemm_bf16(const u16* __restrict__ A, const float* __restrict__ Wf,
               const float* __restrict__ bias, const float* __restrict__ res,
               float* __restrict__ Cf, u16* __restrict__ Cb,
               u16* __restrict__ KbP, u16* __restrict__ VtP, int N)
{
    constexpr int BSTR = KTOT + 4;
    __shared__ u16 Bs[32 * BSTR];
    const int tid  = threadIdx.x;
    const int wave = tid >> 6;
    const int lane = tid & 63;
    const int quad = lane >> 4;
    const int l16  = lane & 15;
    const int m0 = blockIdx.x * 256;
    const int n0 = blockIdx.y * 32;

    // ---- stage W[n0:n0+32, :] fp32 -> bf16, linear & coalesced (once) ----
    {
        constexpr int ITS = (32 * KTOT) / 1024;
        #pragma unroll
        for (int it = 0; it < ITS; ++it) {
            const int e   = it * 1024 + tid * 4;
            const int row = e / KTOT;
            const int col = e & (KTOT - 1);
            const float4 wv = *(const float4*)&Wf[(size_t)(n0 + row) * KTOT + col];
            *(ushort4*)&Bs[row * BSTR + col] = make_ushort4(
                f2bf(wv.x), f2bf(wv.y), f2bf(wv.z), f2bf(wv.w));
        }
    }
    __syncthreads();

    f32x4 acc[4][2] = {};   // [m-quarter][ni]

    const u16* arow[4];
    #pragma unroll
    for (int mt = 0; mt < 4; ++mt)
        arow[mt] = &A[(size_t)(m0 + mt * 64 + wave * 16 + l16) * KTOT];

    #pragma unroll 4
    for (int k0 = 0; k0 < KTOT; k0 += 32) {
        const bf16x8 b0 = *(const bf16x8*)&Bs[l16 * BSTR + k0 + quad * 8];
        const bf16x8 b1 = *(const bf16x8*)&Bs[(16 + l16) * BSTR + k0 + quad * 8];
        #pragma unroll
        for (int mt = 0; mt < 4; ++mt) {
            const bf16x8 a = *(const bf16x8*)&arow[mt][k0 + quad * 8];
            acc[mt][0] = __builtin_amdgcn_mfma_f32_16x16x32_bf16(a, b0, acc[mt][0], 0, 0, 0);
            acc[mt][1] = __builtin_amdgcn_mfma_f32_16x16x32_bf16(a, b1, acc[mt][1], 0, 0, 0);
        }
    }

    // ---- epilogue (all four m-quarters) ----
    #pragma unroll
    for (int mt = 0; mt < 4; ++mt) {
        #pragma unroll
        for (int ni = 0; ni < 2; ++ni) {
            const float bias_v = bias[n0 + ni * 16 + l16];
            #pragma unroll
            for (int r = 0; r < 4; ++r) {
                const int m = m0 + mt * 64 + wave * 16 + quad * 4 + r;
                float v = acc[mt][ni][r] + bias_v;
                if (OUTMODE == 0) {
                    const int n = n0 + ni * 16 + l16;
                    if (RES) v += res[(size_t)m * N + n];
                    Cf[(size_t)m * N + n] = v;
                } else if (OUTMODE == 1) {
                    const int n = n0 + ni * 16 + l16;
                    v = v / (1.0f + __expf(-v));
                    Cb[(size_t)m * N + n] = f2bf(v);
                } else {
                    const int rgn = n0 >> 8;               // 0=Q 1=K 2=V
                    const int nl  = (n0 & 255) + ni * 16 + l16;
                    const int hh  = nl >> 5, dh = nl & 31;
                    const int bb  = m >> 11, s = m & (kS - 1);
                    const int bh  = bb * kH + hh;
                    if (rgn == 0)
                        Cb[((size_t)bh * kS + s) * kDH + dh] = f2bf(v * kScaleL2E);
                    else if (rgn == 1)
                        KbP[((size_t)bh * kS + s) * kDH + dh] = f2bf(v);
                    else {
                        // quad-interleave within 32-key block
                        const int so = s & 31;
                        const int vq = (so >> 2) & 3;
                        const int vj = (so & 3) | (((so >> 4) & 1) << 2);
                        VtP[(((size_t)bh * (kS / 32) + (s >> 5)) * 4 + vq) * 256
                            + dh * 8 + vj] = f2bf(v);
                    }
                }
            }
        }
    }
}

// ---------------------------------------------------------------------------
// MFMA flash attention v17: in-register P (R14) + l VIA MFMA-OF-ONES.
// S^T = mfma(A=K_frag, B=Q_frag); lane packs its query's exp2'd scores
// straight into PV A-frags (quad-interleaved V matches). NEW: the row-sum l
// is accumulated by lacc = mfma(pA, ones) — 4 extra MFMAs/tile on the idle
// MFMA pipe replace ~30 serial adds on the saturated VALU pipe, and
// lacc[qb][r] lands in O's C-layout so the combine needs no shuffles.
// No-max softmax; LDS only for the additive half-combine.
// Block = 4 waves: (qsub=wave>>1)*32 queries x (half=wave&1)*1024 keys.
// Grid (kS/64=32, 8, 4) = 1024 blocks.
// ---------------------------------------------------------------------------
__global__ __launch_bounds__(256)
void attn_kernel(const u16* __restrict__ Qb, const u16* __restrict__ Kb,
                 const u16* __restrict__ Vp, u16* __restrict__ ctx)
{
    __shared__ float cbuf[2][32 * 33];     // combine buffer only (8448 B)
    const int tid  = threadIdx.x;
    const int wave = tid >> 6;
    const int lane = tid & 63;
    const int quad = lane >> 4;
    const int l16  = lane & 15;
    const int h = blockIdx.y;
    const int b = blockIdx.z;
    const int bh = b * kH + h;
    const int qsub = wave >> 1;
    const int half = wave & 1;
    const int q0 = blockIdx.x * 64 + qsub * 32;

    bf16x8 aq[2];
    aq[0] = *(const bf16x8*)&Qb[((size_t)bh * kS + q0 + l16) * kDH + quad * 8];
    aq[1] = *(const bf16x8*)&Qb[((size_t)bh * kS + q0 + 16 + l16) * kDH + quad * 8];

    const u16* Kbase = Kb + (size_t)bh * kS * kDH;
    const u16* Vbase = Vp + (size_t)bh * (kS * 32);

    // constant B-operand of bf16 1.0 for the l row-sum MFMA
    bf16x8 ones;
    #pragma unroll
    for (int i = 0; i < 8; ++i) ones[i] = (short)0x3F80;

    f32x4 O[2][2] = {};
    f32x4 lacc[2] = {};
    const f32x4 zz = {0.f, 0.f, 0.f, 0.f};

    const int kbeg = half * (kS / 2);
    #pragma unroll 1
    for (int kt = kbeg; kt < kbeg + kS / 2; kt += 64) {
        bf16x8 kf[4];
        #pragma unroll
        for (int kg = 0; kg < 4; ++kg)
            kf[kg] = *(const bf16x8*)
                &Kbase[(size_t)(kt + kg * 16 + l16) * kDH + quad * 8];
        bf16x8 vf[2][2];
        #pragma unroll
        for (int ks = 0; ks < 2; ++ks)
            #pragma unroll
            for (int nf = 0; nf < 2; ++nf)
                vf[ks][nf] = *(const bf16x8*)
                    &Vbase[(size_t)(((kt >> 5) + ks) * 4 + quad) * 1024
                           + (nf * 16 + l16) * 8];

        #pragma unroll
        for (int qb = 0; qb < 2; ++qb) {
            f32x4 S[4];
            #pragma unroll
            for (int kg = 0; kg < 4; ++kg)
                S[kg] = __builtin_amdgcn_mfma_f32_16x16x32_bf16(kf[kg], aq[qb], zz, 0, 0, 0);

            float e0[8], e1[8];
            #pragma unroll
            for (int r = 0; r < 4; ++r) {
                e0[r]     = __builtin_amdgcn_exp2f(S[0][r]);
                e0[4 + r] = __builtin_amdgcn_exp2f(S[1][r]);
                e1[r]     = __builtin_amdgcn_exp2f(S[2][r]);
                e1[4 + r] = __builtin_amdgcn_exp2f(S[3][r]);
            }
            union { u32 u[4]; bf16x8 v; } pA0, pA1;
            pA0.u[0] = pk_trunc(e0[0], e0[1]);
            pA0.u[1] = pk_trunc(e0[2], e0[3]);
            pA0.u[2] = pk_trunc(e0[4], e0[5]);
            pA0.u[3] = pk_trunc(e0[6], e0[7]);
            pA1.u[0] = pk_trunc(e1[0], e1[1]);
            pA1.u[1] = pk_trunc(e1[2], e1[3]);
            pA1.u[2] = pk_trunc(e1[4], e1[5]);
            pA1.u[3] = pk_trunc(e1[6], e1[7]);

            O[qb][0] = __builtin_amdgcn_mfma_f32_16x16x32_bf16(pA0.v, vf[0][0], O[qb][0], 0, 0, 0);
            O[qb][1] = __builtin_amdgcn_mfma_f32_16x16x32_bf16(pA0.v, vf[0][1], O[qb][1], 0, 0, 0);
            lacc[qb] = __builtin_amdgcn_mfma_f32_16x16x32_bf16(pA0.v, ones, lacc[qb], 0, 0, 0);
            O[qb][0] = __builtin_amdgcn_mfma_f32_16x16x32_bf16(pA1.v, vf[1][0], O[qb][0], 0, 0, 0);
            O[qb][1] = __builtin_amdgcn_mfma_f32_16x16x32_bf16(pA1.v, vf[1][1], O[qb][1], 0, 0, 0);
            lacc[qb] = __builtin_amdgcn_mfma_f32_16x16x32_bf16(pA1.v, ones, lacc[qb], 0, 0, 0);
        }
    }

    // ---- combine the two key-halves (lacc shares O's C-layout: no shuffles)
    float* cb = cbuf[qsub];
    if (half == 1) {
        #pragma unroll
        for (int qb = 0; qb < 2; ++qb)
            #pragma unroll
            for (int r = 0; r < 4; ++r) {
                const int row = qb * 16 + quad * 4 + r;
                cb[row * 33 + l16]      = O[qb][0][r];
                cb[row * 33 + 16 + l16] = O[qb][1][r];
                if (l16 == 0) cb[row * 33 + 32] = lacc[qb][r];
            }
    }
    __syncthreads();
    if (half == 0) {
        #pragma unroll
        for (int qb = 0; qb < 2; ++qb)
            #pragma unroll
            for (int r = 0; r < 4; ++r) {
                const int row = qb * 16 + quad * 4 + r;
                const float lq  = lacc[qb][r] + cb[row * 33 + 32];
                const float inv = 1.0f / lq;
                const float o0 = O[qb][0][r] + cb[row * 33 + l16];
                const float o1 = O[qb][1][r] + cb[row * 33 + 16 + l16];
                const int q = q0 + row;
                u16* crow = ctx + ((size_t)(b * kS + q)) * kD + h * kDH;
                crow[l16]      = f2bf(o0 * inv);
                crow[16 + l16] = f2bf(o1 * inv);
            }
    }
}

// ---------------------------------------------------------------------------
// 7 dispatches: ln1 -> qkv -> attn -> proj(+res) -> ln2 -> ffn1(SiLU) ->
// ffn2(+res). Workspace (bytes):
//   [ 0M, 4M)  Qb   (bf16)  -- [0,8M) reused as h after attn
//   [ 4M, 8M)  Kb   (bf16)
//   [ 8M,12M)  Vp   (bf16, quad-interleaved)
//   [12M,16M)  ctx  (bf16)
//   [16M,20M)  y    (bf16, LN1 then LN2)
// ---------------------------------------------------------------------------
extern "C" void kernel_launch(void* const* d_in, const int* in_sizes, int n_in,
                              void* d_out, int out_size, void* d_ws, size_t ws_size,
                              hipStream_t stream)
{
    const float* x      = (const float*)d_in[0];
    const float* ln1_g  = (const float*)d_in[1];
    const float* ln1_b  = (const float*)d_in[2];
    const float* w_qkv  = (const float*)d_in[3];
    const float* b_qkv  = (const float*)d_in[4];
    const float* w_proj = (const float*)d_in[5];
    const float* b_proj = (const float*)d_in[6];
    const float* ln2_g  = (const float*)d_in[7];
    const float* ln2_b  = (const float*)d_in[8];
    const float* w1     = (const float*)d_in[9];
    const float* b1     = (const float*)d_in[10];
    const float* w2     = (const float*)d_in[11];
    const float* b2     = (const float*)d_in[12];
    float* out = (float*)d_out;

    char* ws = (char*)d_ws;
    u16* Qb  = (u16*)ws;
    u16* Kb  = (u16*)(ws + ((size_t)4  << 20));
    u16* Vp  = (u16*)(ws + ((size_t)8  << 20));
    u16* ctx = (u16*)(ws + ((size_t)12 << 20));
    u16* y   = (u16*)(ws + ((size_t)16 << 20));
    u16* h   = (u16*)ws;                     // aliases Qb/Kb (dead after attn)

    const dim3 blk(256);

    // 1) y = bf16(LN1(x))
    ln_kernel<<<dim3(kM / 4), blk, 0, stream>>>(x, ln1_g, ln1_b, y);
    // 2) Qb/Kb/Vp = bf16(y @ w_qkv.T + b_qkv), Q pre-scaled, V interleaved
    gemm_bf16<2, false, 256><<<dim3(kM / 256, 24), blk, 0, stream>>>(
        y, w_qkv, b_qkv, nullptr, nullptr, Qb, Kb, Vp, 0);
    // 3) ctx = attention (bf16 out), in-register P + l-via-MFMA
    attn_kernel<<<dim3(kS / 64, kH, kB), blk, 0, stream>>>(Qb, Kb, Vp, ctx);
    // 4) out = x + ctx @ w_proj.T + b_proj   (fp32)
    gemm_bf16<0, true, 256><<<dim3(kM / 256, kD / 32), blk, 0, stream>>>(
        ctx, w_proj, b_proj, x, out, nullptr, nullptr, nullptr, kD);
    // 5) y = bf16(LN2(out))
    ln_kernel<<<dim3(kM / 4), blk, 0, stream>>>(out, ln2_g, ln2_b, y);
    // 6) h = bf16(silu(y @ w1.T + b1))
    gemm_bf16<1, false, 256><<<dim3(kM / 256, kDFF / 32), blk, 0, stream>>>(
        y, w1, b1, nullptr, nullptr, h, nullptr, nullptr, kDFF);
    // 7) out = out + h @ w2.T + b2   (fp32, K=512)
    gemm_bf16<0, true, 512><<<dim3(kM / 256, kD / 32), blk, 0, stream>>>(
        h, w2, b2, out, out, nullptr, nullptr, nullptr, kD);
}

// Round 18
// 169.565 us; speedup vs baseline: 1.5800x; 1.0864x over previous
//
#include <hip/hip_runtime.h>
#include <cstddef>

// Problem constants (B=4, S=2048, D=256, H=8, dh=32, d_ff=512), fp32 in/out.
constexpr int kB   = 4;
constexpr int kS   = 2048;
constexpr int kD   = 256;
constexpr int kH   = 8;
constexpr int kDH  = 32;
constexpr int kDFF = 512;
constexpr int kM   = kB * kS;   // 8192 token rows
constexpr float kEps = 1e-5f;
// 1/sqrt(32) * log2(e): scores pre-scaled so softmax uses exp2 directly.
constexpr float kScaleL2E = 0.17677669529663687f * 1.4426950408889634f;

typedef float f32x4  __attribute__((ext_vector_type(4)));
typedef short bf16x8 __attribute__((ext_vector_type(8)));
typedef unsigned short u16;
typedef unsigned int   u32;

__device__ inline u16 f2bf(float x) {
    union { float f; unsigned u; } c; c.f = x;
    const unsigned r = c.u + 0x7fffu + ((c.u >> 16) & 1u);
    return (u16)(r >> 16);
}

// pack two fp32 -> two bf16 (truncation) in ONE v_perm_b32.
__device__ inline u32 pk_trunc(float lo, float hi) {
    union { float f; u32 u; } a, b; a.f = lo; b.f = hi;
    return __builtin_amdgcn_perm(b.u, a.u, 0x07060302u);
}

// ---------------------------------------------------------------------------
// LayerNorm: 4 rows/block, one wave per row, 4 floats/lane, pure-shuffle
// reduction. bf16 out. (R6/R14-proven.)
// ---------------------------------------------------------------------------
__global__ __launch_bounds__(256)
void ln_kernel(const float* __restrict__ x, const float* __restrict__ g,
               const float* __restrict__ b, u16* __restrict__ y)
{
    const int wave = threadIdx.x >> 6;
    const int lane = threadIdx.x & 63;
    const int row  = blockIdx.x * 4 + wave;
    const float4 v = *(const float4*)&x[(size_t)row * kD + lane * 4];
    float s1 = (v.x + v.y) + (v.z + v.w);
    float s2 = (v.x * v.x + v.y * v.y) + (v.z * v.z + v.w * v.w);
    #pragma unroll
    for (int off = 1; off < 64; off <<= 1) {
        s1 += __shfl_xor(s1, off);
        s2 += __shfl_xor(s2, off);
    }
    const float mu  = s1 * (1.0f / kD);
    const float var = s2 * (1.0f / kD) - mu * mu;
    const float inv = rsqrtf(var + kEps);
    const float4 g4 = *(const float4*)&g[lane * 4];
    const float4 b4 = *(const float4*)&b[lane * 4];
    *(ushort4*)&y[(size_t)row * kD + lane * 4] = make_ushort4(
        f2bf((v.x - mu) * inv * g4.x + b4.x),
        f2bf((v.y - mu) * inv * g4.y + b4.y),
        f2bf((v.z - mu) * inv * g4.z + b4.z),
        f2bf((v.w - mu) * inv * g4.w + b4.w));
}

// ---------------------------------------------------------------------------
// bf16 MFMA NT GEMM, M-pair fused K-loop (R14-proven, byte-identical).
// Block tile 128(M) x NT(N), 4 waves; wave w owns rows [m0+16w,+16) and
// [m0+64+16w,+16). W fp32 -> bf16 during linear coalesced LDS staging (once);
// barrier-free K-loop; each staged B-fragment read feeds TWO MFMAs.
// LDS stride KTOT+4 (2-way bank aliasing = free).
// OUTMODE: 0 = fp32 (+RES), 1 = SiLU->bf16, 2 = QKV split:
//   Qb[bh][s][dh] (pre-scaled kScaleL2E), Kb[bh][s][dh],
//   Vp = quad-interleaved V: key so -> slot (vq=(so>>2)&3,
//   vj=(so&3)|(((so>>4)&1)<<2)), stored [bh][s/32][vq][dh][8].
// ---------------------------------------------------------------------------
template<int NT, int OUTMODE, bool RES, int KTOT>
__global__ __launch_bounds__(256)
void gemm_bf16(const u16* __restrict__ A, const float* __restrict__ Wf,
               const float* __restrict__ bias, const float* __restrict__ res,
               float* __restrict__ Cf, u16* __restrict__ Cb,
               u16* __restrict__ KbP, u16* __restrict__ VtP, int N)
{
    constexpr int BSTR = KTOT + 4;
    __shared__ u16 Bs[NT * BSTR];
    const int tid  = threadIdx.x;
    const int wave = tid >> 6;
    const int lane = tid & 63;
    const int quad = lane >> 4;
    const int l16  = lane & 15;
    const int m0 = blockIdx.x * 128;
    const int n0 = blockIdx.y * NT;

    // ---- stage W[n0:n0+NT, :] fp32 -> bf16, linear & coalesced (once) ----
    {
        constexpr int ITS = (NT * KTOT) / 1024;
        #pragma unroll
        for (int it = 0; it < ITS; ++it) {
            const int e   = it * 1024 + tid * 4;
            const int row = e / KTOT;
            const int col = e & (KTOT - 1);
            const float4 wv = *(const float4*)&Wf[(size_t)(n0 + row) * KTOT + col];
            *(ushort4*)&Bs[row * BSTR + col] = make_ushort4(
                f2bf(wv.x), f2bf(wv.y), f2bf(wv.z), f2bf(wv.w));
        }
    }
    __syncthreads();

    f32x4 acc[2][NT / 16];
    #pragma unroll
    for (int mt = 0; mt < 2; ++mt)
        #pragma unroll
        for (int ni = 0; ni < NT / 16; ++ni) acc[mt][ni] = {0.f, 0.f, 0.f, 0.f};

    const u16* arow0 = &A[(size_t)(m0 + wave * 16 + l16) * KTOT];
    const u16* arow1 = &A[(size_t)(m0 + 64 + wave * 16 + l16) * KTOT];
    #pragma unroll 4
    for (int k0 = 0; k0 < KTOT; k0 += 32) {
        const bf16x8 a0 = *(const bf16x8*)&arow0[k0 + quad * 8];
        const bf16x8 a1 = *(const bf16x8*)&arow1[k0 + quad * 8];
        #pragma unroll
        for (int ni = 0; ni < NT / 16; ++ni) {
            const bf16x8 bf = *(const bf16x8*)&Bs[(ni * 16 + l16) * BSTR + k0 + quad * 8];
            acc[0][ni] = __builtin_amdgcn_mfma_f32_16x16x32_bf16(a0, bf, acc[0][ni], 0, 0, 0);
            acc[1][ni] = __builtin_amdgcn_mfma_f32_16x16x32_bf16(a1, bf, acc[1][ni], 0, 0, 0);
        }
    }

    // ---- epilogue (both m-halves) ----
    #pragma unroll
    for (int mt = 0; mt < 2; ++mt) {
        #pragma unroll
        for (int ni = 0; ni < NT / 16; ++ni) {
            const float bias_v = bias[n0 + ni * 16 + l16];
            #pragma unroll
            for (int r = 0; r < 4; ++r) {
                const int m = m0 + mt * 64 + wave * 16 + quad * 4 + r;
                float v = acc[mt][ni][r] + bias_v;
                if (OUTMODE == 0) {
                    const int n = n0 + ni * 16 + l16;
                    if (RES) v += res[(size_t)m * N + n];
                    Cf[(size_t)m * N + n] = v;
                } else if (OUTMODE == 1) {
                    const int n = n0 + ni * 16 + l16;
                    v = v / (1.0f + __expf(-v));
                    Cb[(size_t)m * N + n] = f2bf(v);
                } else {
                    const int rgn = n0 >> 8;               // 0=Q 1=K 2=V
                    const int nl  = (n0 & 255) + ni * 16 + l16;
                    const int hh  = nl >> 5, dh = nl & 31;
                    const int bb  = m >> 11, s = m & (kS - 1);
                    const int bh  = bb * kH + hh;
                    if (rgn == 0)
                        Cb[((size_t)bh * kS + s) * kDH + dh] = f2bf(v * kScaleL2E);
                    else if (rgn == 1)
                        KbP[((size_t)bh * kS + s) * kDH + dh] = f2bf(v);
                    else {
                        // quad-interleave within 32-key block
                        const int so = s & 31;
                        const int vq = (so >> 2) & 3;
                        const int vj = (so & 3) | (((so >> 4) & 1) << 2);
                        VtP[(((size_t)bh * (kS / 32) + (s >> 5)) * 4 + vq) * 256
                            + dh * 8 + vj] = f2bf(v);
                    }
                }
            }
        }
    }
}

// ---------------------------------------------------------------------------
// MFMA flash attention v18 = R14 (in-register P, raw v_exp_f32, zero
// main-loop LDS) + l VIA MFMA-OF-ONES (sole change this round):
// lacc = mfma(pA, ones) accumulates the row-sum l on the 12%-utilized MFMA
// pipe instead of ~30 serial adds/tile on the 70%-busy VALU pipe; lacc lands
// in O's C-layout so the combine needs no shuffles (verified correct in R17).
// Block = 4 waves: (qsub=wave>>1)*32 queries x (half=wave&1)*1024 keys.
// Grid (kS/64=32, 8, 4) = 1024 blocks.
// ---------------------------------------------------------------------------
__global__ __launch_bounds__(256)
void attn_kernel(const u16* __restrict__ Qb, const u16* __restrict__ Kb,
                 const u16* __restrict__ Vp, u16* __restrict__ ctx)
{
    __shared__ float cbuf[2][32 * 33];     // combine buffer only (8448 B)
    const int tid  = threadIdx.x;
    const int wave = tid >> 6;
    const int lane = tid & 63;
    const int quad = lane >> 4;
    const int l16  = lane & 15;
    const int h = blockIdx.y;
    const int b = blockIdx.z;
    const int bh = b * kH + h;
    const int qsub = wave >> 1;
    const int half = wave & 1;
    const int q0 = blockIdx.x * 64 + qsub * 32;

    bf16x8 aq[2];
    aq[0] = *(const bf16x8*)&Qb[((size_t)bh * kS + q0 + l16) * kDH + quad * 8];
    aq[1] = *(const bf16x8*)&Qb[((size_t)bh * kS + q0 + 16 + l16) * kDH + quad * 8];

    const u16* Kbase = Kb + (size_t)bh * kS * kDH;
    const u16* Vbase = Vp + (size_t)bh * (kS * 32);

    bf16x8 ones;
    #pragma unroll
    for (int i = 0; i < 8; ++i) ones[i] = (short)0x3F80;   // bf16 1.0

    f32x4 O[2][2] = {};
    f32x4 lacc[2] = {};
    const f32x4 zz = {0.f, 0.f, 0.f, 0.f};

    const int kbeg = half * (kS / 2);
    #pragma unroll 1
    for (int kt = kbeg; kt < kbeg + kS / 2; kt += 64) {
        bf16x8 kf[4];
        #pragma unroll
        for (int kg = 0; kg < 4; ++kg)
            kf[kg] = *(const bf16x8*)
                &Kbase[(size_t)(kt + kg * 16 + l16) * kDH + quad * 8];
        bf16x8 vf[2][2];
        #pragma unroll
        for (int ks = 0; ks < 2; ++ks)
            #pragma unroll
            for (int nf = 0; nf < 2; ++nf)
                vf[ks][nf] = *(const bf16x8*)
                    &Vbase[(size_t)(((kt >> 5) + ks) * 4 + quad) * 1024
                           + (nf * 16 + l16) * 8];

        #pragma unroll
        for (int qb = 0; qb < 2; ++qb) {
            f32x4 S[4];
            #pragma unroll
            for (int kg = 0; kg < 4; ++kg)
                S[kg] = __builtin_amdgcn_mfma_f32_16x16x32_bf16(kf[kg], aq[qb], zz, 0, 0, 0);

            float e0[8], e1[8];
            #pragma unroll
            for (int r = 0; r < 4; ++r) {
                e0[r]     = __builtin_amdgcn_exp2f(S[0][r]);
                e0[4 + r] = __builtin_amdgcn_exp2f(S[1][r]);
                e1[r]     = __builtin_amdgcn_exp2f(S[2][r]);
                e1[4 + r] = __builtin_amdgcn_exp2f(S[3][r]);
            }
            union { u32 u[4]; bf16x8 v; } pA0, pA1;
            pA0.u[0] = pk_trunc(e0[0], e0[1]);
            pA0.u[1] = pk_trunc(e0[2], e0[3]);
            pA0.u[2] = pk_trunc(e0[4], e0[5]);
            pA0.u[3] = pk_trunc(e0[6], e0[7]);
            pA1.u[0] = pk_trunc(e1[0], e1[1]);
            pA1.u[1] = pk_trunc(e1[2], e1[3]);
            pA1.u[2] = pk_trunc(e1[4], e1[5]);
            pA1.u[3] = pk_trunc(e1[6], e1[7]);

            O[qb][0] = __builtin_amdgcn_mfma_f32_16x16x32_bf16(pA0.v, vf[0][0], O[qb][0], 0, 0, 0);
            O[qb][1] = __builtin_amdgcn_mfma_f32_16x16x32_bf16(pA0.v, vf[0][1], O[qb][1], 0, 0, 0);
            lacc[qb] = __builtin_amdgcn_mfma_f32_16x16x32_bf16(pA0.v, ones, lacc[qb], 0, 0, 0);
            O[qb][0] = __builtin_amdgcn_mfma_f32_16x16x32_bf16(pA1.v, vf[1][0], O[qb][0], 0, 0, 0);
            O[qb][1] = __builtin_amdgcn_mfma_f32_16x16x32_bf16(pA1.v, vf[1][1], O[qb][1], 0, 0, 0);
            lacc[qb] = __builtin_amdgcn_mfma_f32_16x16x32_bf16(pA1.v, ones, lacc[qb], 0, 0, 0);
        }
    }

    // ---- combine the two key-halves (lacc shares O's C-layout: no shuffles)
    float* cb = cbuf[qsub];
    if (half == 1) {
        #pragma unroll
        for (int qb = 0; qb < 2; ++qb)
            #pragma unroll
            for (int r = 0; r < 4; ++r) {
                const int row = qb * 16 + quad * 4 + r;
                cb[row * 33 + l16]      = O[qb][0][r];
                cb[row * 33 + 16 + l16] = O[qb][1][r];
                if (l16 == 0) cb[row * 33 + 32] = lacc[qb][r];
            }
    }
    __syncthreads();
    if (half == 0) {
        #pragma unroll
        for (int qb = 0; qb < 2; ++qb)
            #pragma unroll
            for (int r = 0; r < 4; ++r) {
                const int row = qb * 16 + quad * 4 + r;
                const float lq  = lacc[qb][r] + cb[row * 33 + 32];
                const float inv = 1.0f / lq;
                const float o0 = O[qb][0][r] + cb[row * 33 + l16];
                const float o1 = O[qb][1][r] + cb[row * 33 + 16 + l16];
                const int q = q0 + row;
                u16* crow = ctx + ((size_t)(b * kS + q)) * kD + h * kDH;
                crow[l16]      = f2bf(o0 * inv);
                crow[16 + l16] = f2bf(o1 * inv);
            }
    }
}

// ---------------------------------------------------------------------------
// 7 dispatches: ln1 -> qkv -> attn -> proj(+res) -> ln2 -> ffn1(SiLU) ->
// ffn2(+res). Workspace (bytes):
//   [ 0M, 4M)  Qb   (bf16)  -- [0,8M) reused as h after attn
//   [ 4M, 8M)  Kb   (bf16)
//   [ 8M,12M)  Vp   (bf16, quad-interleaved)
//   [12M,16M)  ctx  (bf16)
//   [16M,20M)  y    (bf16, LN1 then LN2)
// ---------------------------------------------------------------------------
extern "C" void kernel_launch(void* const* d_in, const int* in_sizes, int n_in,
                              void* d_out, int out_size, void* d_ws, size_t ws_size,
                              hipStream_t stream)
{
    const float* x      = (const float*)d_in[0];
    const float* ln1_g  = (const float*)d_in[1];
    const float* ln1_b  = (const float*)d_in[2];
    const float* w_qkv  = (const float*)d_in[3];
    const float* b_qkv  = (const float*)d_in[4];
    const float* w_proj = (const float*)d_in[5];
    const float* b_proj = (const float*)d_in[6];
    const float* ln2_g  = (const float*)d_in[7];
    const float* ln2_b  = (const float*)d_in[8];
    const float* w1     = (const float*)d_in[9];
    const float* b1     = (const float*)d_in[10];
    const float* w2     = (const float*)d_in[11];
    const float* b2     = (const float*)d_in[12];
    float* out = (float*)d_out;

    char* ws = (char*)d_ws;
    u16* Qb  = (u16*)ws;
    u16* Kb  = (u16*)(ws + ((size_t)4  << 20));
    u16* Vp  = (u16*)(ws + ((size_t)8  << 20));
    u16* ctx = (u16*)(ws + ((size_t)12 << 20));
    u16* y   = (u16*)(ws + ((size_t)16 << 20));
    u16* h   = (u16*)ws;                     // aliases Qb/Kb (dead after attn)

    const dim3 blk(256);

    // 1) y = bf16(LN1(x))
    ln_kernel<<<dim3(kM / 4), blk, 0, stream>>>(x, ln1_g, ln1_b, y);
    // 2) Qb/Kb/Vp = bf16(y @ w_qkv.T + b_qkv), Q pre-scaled, V interleaved
    gemm_bf16<64, 2, false, 256><<<dim3(kM / 128, 12), blk, 0, stream>>>(
        y, w_qkv, b_qkv, nullptr, nullptr, Qb, Kb, Vp, 0);
    // 3) ctx = attention (bf16 out), in-register P + l-via-MFMA
    attn_kernel<<<dim3(kS / 64, kH, kB), blk, 0, stream>>>(Qb, Kb, Vp, ctx);
    // 4) out = x + ctx @ w_proj.T + b_proj   (fp32)
    gemm_bf16<32, 0, true, 256><<<dim3(kM / 128, kD / 32), blk, 0, stream>>>(
        ctx, w_proj, b_proj, x, out, nullptr, nullptr, nullptr, kD);
    // 5) y = bf16(LN2(out))
    ln_kernel<<<dim3(kM / 4), blk, 0, stream>>>(out, ln2_g, ln2_b, y);
    // 6) h = bf16(silu(y @ w1.T + b1))
    gemm_bf16<64, 1, false, 256><<<dim3(kM / 128, kDFF / 64), blk, 0, stream>>>(
        y, w1, b1, nullptr, nullptr, h, nullptr, nullptr, kDFF);
    // 7) out = out + h @ w2.T + b2   (fp32, K=512)
    gemm_bf16<32, 0, true, 512><<<dim3(kM / 128, kD / 32), blk, 0, stream>>>(
        h, w2, b2, out, out, nullptr, nullptr, nullptr, kD);
}

// Round 19
// 168.391 us; speedup vs baseline: 1.5910x; 1.0070x over previous
//
#include <hip/hip_runtime.h>
#include <cstddef>

// Problem constants (B=4, S=2048, D=256, H=8, dh=32, d_ff=512), fp32 in/out.
constexpr int kB   = 4;
constexpr int kS   = 2048;
constexpr int kD   = 256;
constexpr int kH   = 8;
constexpr int kDH  = 32;
constexpr int kDFF = 512;
constexpr int kM   = kB * kS;   // 8192 token rows
constexpr float kEps = 1e-5f;
// 1/sqrt(32) * log2(e): scores pre-scaled so softmax uses exp2 directly.
constexpr float kScaleL2E = 0.17677669529663687f * 1.4426950408889634f;

typedef float f32x4  __attribute__((ext_vector_type(4)));
typedef short bf16x8 __attribute__((ext_vector_type(8)));
typedef unsigned short u16;
typedef unsigned int   u32;

__device__ inline u16 f2bf(float x) {
    union { float f; unsigned u; } c; c.f = x;
    const unsigned r = c.u + 0x7fffu + ((c.u >> 16) & 1u);
    return (u16)(r >> 16);
}

// pack two fp32 -> two bf16 (truncation) in ONE v_perm_b32.
__device__ inline u32 pk_trunc(float lo, float hi) {
    union { float f; u32 u; } a, b; a.f = lo; b.f = hi;
    return __builtin_amdgcn_perm(b.u, a.u, 0x07060302u);
}

// ---------------------------------------------------------------------------
// LayerNorm: 4 rows/block, one wave per row, 4 floats/lane, pure-shuffle
// reduction. bf16 out. (R6/R14-proven.)
// ---------------------------------------------------------------------------
__global__ __launch_bounds__(256)
void ln_kernel(const float* __restrict__ x, const float* __restrict__ g,
               const float* __restrict__ b, u16* __restrict__ y)
{
    const int wave = threadIdx.x >> 6;
    const int lane = threadIdx.x & 63;
    const int row  = blockIdx.x * 4 + wave;
    const float4 v = *(const float4*)&x[(size_t)row * kD + lane * 4];
    float s1 = (v.x + v.y) + (v.z + v.w);
    float s2 = (v.x * v.x + v.y * v.y) + (v.z * v.z + v.w * v.w);
    #pragma unroll
    for (int off = 1; off < 64; off <<= 1) {
        s1 += __shfl_xor(s1, off);
        s2 += __shfl_xor(s2, off);
    }
    const float mu  = s1 * (1.0f / kD);
    const float var = s2 * (1.0f / kD) - mu * mu;
    const float inv = rsqrtf(var + kEps);
    const float4 g4 = *(const float4*)&g[lane * 4];
    const float4 b4 = *(const float4*)&b[lane * 4];
    *(ushort4*)&y[(size_t)row * kD + lane * 4] = make_ushort4(
        f2bf((v.x - mu) * inv * g4.x + b4.x),
        f2bf((v.y - mu) * inv * g4.y + b4.y),
        f2bf((v.z - mu) * inv * g4.z + b4.z),
        f2bf((v.w - mu) * inv * g4.w + b4.w));
}

// ---------------------------------------------------------------------------
// bf16 MFMA NT GEMM, M-pair fused K-loop (R14-proven, byte-identical).
// Block tile 128(M) x NT(N), 4 waves; wave w owns rows [m0+16w,+16) and
// [m0+64+16w,+16). W fp32 -> bf16 during linear coalesced LDS staging (once);
// barrier-free K-loop; each staged B-fragment read feeds TWO MFMAs.
// LDS stride KTOT+4 (2-way bank aliasing = free).
// OUTMODE: 0 = fp32 (+RES), 1 = SiLU->bf16, 2 = QKV split:
//   Qb[bh][s][dh] (pre-scaled kScaleL2E), Kb[bh][s][dh],
//   Vp = quad-interleaved V: key so -> slot (vq=(so>>2)&3,
//   vj=(so&3)|(((so>>4)&1)<<2)), stored [bh][s/32][vq][dh][8].
// ---------------------------------------------------------------------------
template<int NT, int OUTMODE, bool RES, int KTOT>
__global__ __launch_bounds__(256)
void gemm_bf16(const u16* __restrict__ A, const float* __restrict__ Wf,
               const float* __restrict__ bias, const float* __restrict__ res,
               float* __restrict__ Cf, u16* __restrict__ Cb,
               u16* __restrict__ KbP, u16* __restrict__ VtP, int N)
{
    constexpr int BSTR = KTOT + 4;
    __shared__ u16 Bs[NT * BSTR];
    const int tid  = threadIdx.x;
    const int wave = tid >> 6;
    const int lane = tid & 63;
    const int quad = lane >> 4;
    const int l16  = lane & 15;
    const int m0 = blockIdx.x * 128;
    const int n0 = blockIdx.y * NT;

    // ---- stage W[n0:n0+NT, :] fp32 -> bf16, linear & coalesced (once) ----
    {
        constexpr int ITS = (NT * KTOT) / 1024;
        #pragma unroll
        for (int it = 0; it < ITS; ++it) {
            const int e   = it * 1024 + tid * 4;
            const int row = e / KTOT;
            const int col = e & (KTOT - 1);
            const float4 wv = *(const float4*)&Wf[(size_t)(n0 + row) * KTOT + col];
            *(ushort4*)&Bs[row * BSTR + col] = make_ushort4(
                f2bf(wv.x), f2bf(wv.y), f2bf(wv.z), f2bf(wv.w));
        }
    }
    __syncthreads();

    f32x4 acc[2][NT / 16];
    #pragma unroll
    for (int mt = 0; mt < 2; ++mt)
        #pragma unroll
        for (int ni = 0; ni < NT / 16; ++ni) acc[mt][ni] = {0.f, 0.f, 0.f, 0.f};

    const u16* arow0 = &A[(size_t)(m0 + wave * 16 + l16) * KTOT];
    const u16* arow1 = &A[(size_t)(m0 + 64 + wave * 16 + l16) * KTOT];
    #pragma unroll 4
    for (int k0 = 0; k0 < KTOT; k0 += 32) {
        const bf16x8 a0 = *(const bf16x8*)&arow0[k0 + quad * 8];
        const bf16x8 a1 = *(const bf16x8*)&arow1[k0 + quad * 8];
        #pragma unroll
        for (int ni = 0; ni < NT / 16; ++ni) {
            const bf16x8 bf = *(const bf16x8*)&Bs[(ni * 16 + l16) * BSTR + k0 + quad * 8];
            acc[0][ni] = __builtin_amdgcn_mfma_f32_16x16x32_bf16(a0, bf, acc[0][ni], 0, 0, 0);
            acc[1][ni] = __builtin_amdgcn_mfma_f32_16x16x32_bf16(a1, bf, acc[1][ni], 0, 0, 0);
        }
    }

    // ---- epilogue (both m-halves) ----
    #pragma unroll
    for (int mt = 0; mt < 2; ++mt) {
        #pragma unroll
        for (int ni = 0; ni < NT / 16; ++ni) {
            const float bias_v = bias[n0 + ni * 16 + l16];
            #pragma unroll
            for (int r = 0; r < 4; ++r) {
                const int m = m0 + mt * 64 + wave * 16 + quad * 4 + r;
                float v = acc[mt][ni][r] + bias_v;
                if (OUTMODE == 0) {
                    const int n = n0 + ni * 16 + l16;
                    if (RES) v += res[(size_t)m * N + n];
                    Cf[(size_t)m * N + n] = v;
                } else if (OUTMODE == 1) {
                    const int n = n0 + ni * 16 + l16;
                    v = v / (1.0f + __expf(-v));
                    Cb[(size_t)m * N + n] = f2bf(v);
                } else {
                    const int rgn = n0 >> 8;               // 0=Q 1=K 2=V
                    const int nl  = (n0 & 255) + ni * 16 + l16;
                    const int hh  = nl >> 5, dh = nl & 31;
                    const int bb  = m >> 11, s = m & (kS - 1);
                    const int bh  = bb * kH + hh;
                    if (rgn == 0)
                        Cb[((size_t)bh * kS + s) * kDH + dh] = f2bf(v * kScaleL2E);
                    else if (rgn == 1)
                        KbP[((size_t)bh * kS + s) * kDH + dh] = f2bf(v);
                    else {
                        // quad-interleave within 32-key block
                        const int so = s & 31;
                        const int vq = (so >> 2) & 3;
                        const int vj = (so & 3) | (((so >> 4) & 1) << 2);
                        VtP[(((size_t)bh * (kS / 32) + (s >> 5)) * 4 + vq) * 256
                            + dh * 8 + vj] = f2bf(v);
                    }
                }
            }
        }
    }
}

// ---------------------------------------------------------------------------
// MFMA flash attention v19 = R14 inner loop (in-register P, raw v_exp_f32,
// zero main-loop LDS, VALU l-adds) with a 4-WAY KEY SPLIT for occupancy:
// block = 32 queries of one (b,h); wave w handles key quarter [w*512,+512).
// Grid (kS/32=64, 8, 4) = 2048 blocks -> 8 blocks/CU (R14's 1024-block grid
// capped occupancy at 4 blocks/CU / ~27%; VGPR 64 + LDS 12.7 KB allow 8).
// No-max softmax => partials combine by pure addition: waves 1..3 park
// (O, l) in LDS, wave 0 sums, normalizes, stores ctx bf16.
// ---------------------------------------------------------------------------
__global__ __launch_bounds__(256)
void attn_kernel(const u16* __restrict__ Qb, const u16* __restrict__ Kb,
                 const u16* __restrict__ Vp, u16* __restrict__ ctx)
{
    __shared__ float cbuf[3][32 * 33];     // combine buffer only (12672 B)
    const int tid  = threadIdx.x;
    const int wave = tid >> 6;             // key quarter
    const int lane = tid & 63;
    const int quad = lane >> 4;
    const int l16  = lane & 15;
    const int h = blockIdx.y;
    const int b = blockIdx.z;
    const int bh = b * kH + h;
    const int q0 = blockIdx.x * 32;

    // Q fragments double as MFMA B-operands (B[k=dh=quad*8+j][n=query=l16]).
    bf16x8 aq[2];
    aq[0] = *(const bf16x8*)&Qb[((size_t)bh * kS + q0 + l16) * kDH + quad * 8];
    aq[1] = *(const bf16x8*)&Qb[((size_t)bh * kS + q0 + 16 + l16) * kDH + quad * 8];

    const u16* Kbase = Kb + (size_t)bh * kS * kDH;
    const u16* Vbase = Vp + (size_t)bh * (kS * 32);

    f32x4 O[2][2] = {};
    float lp[2] = {0.f, 0.f};
    const f32x4 zz = {0.f, 0.f, 0.f, 0.f};

    const int kbeg = wave * (kS / 4);
    #pragma unroll 1
    for (int kt = kbeg; kt < kbeg + kS / 4; kt += 64) {
        // K A-frags: natural key order, coalesced (A[m=key=l16][k=dh]).
        bf16x8 kf[4];
        #pragma unroll
        for (int kg = 0; kg < 4; ++kg)
            kf[kg] = *(const bf16x8*)
                &Kbase[(size_t)(kt + kg * 16 + l16) * kDH + quad * 8];
        // V B-frags: quad-interleaved layout -> contiguous 16-B per lane.
        bf16x8 vf[2][2];
        #pragma unroll
        for (int ks = 0; ks < 2; ++ks)
            #pragma unroll
            for (int nf = 0; nf < 2; ++nf)
                vf[ks][nf] = *(const bf16x8*)
                    &Vbase[(size_t)(((kt >> 5) + ks) * 4 + quad) * 1024
                           + (nf * 16 + l16) * 8];

        #pragma unroll
        for (int qb = 0; qb < 2; ++qb) {
            // S^T[key][query]: operand-swapped MFMA.
            f32x4 S[4];
            #pragma unroll
            for (int kg = 0; kg < 4; ++kg)
                S[kg] = __builtin_amdgcn_mfma_f32_16x16x32_bf16(kf[kg], aq[qb], zz, 0, 0, 0);

            // raw v_exp_f32 + in-register pack into PV A-frags.
            float e0[8], e1[8];
            #pragma unroll
            for (int r = 0; r < 4; ++r) {
                e0[r]     = __builtin_amdgcn_exp2f(S[0][r]);
                e0[4 + r] = __builtin_amdgcn_exp2f(S[1][r]);
                e1[r]     = __builtin_amdgcn_exp2f(S[2][r]);
                e1[4 + r] = __builtin_amdgcn_exp2f(S[3][r]);
            }
            lp[qb] += ((e0[0] + e0[1]) + (e0[2] + e0[3]))
                    + ((e0[4] + e0[5]) + (e0[6] + e0[7]))
                    + ((e1[0] + e1[1]) + (e1[2] + e1[3]))
                    + ((e1[4] + e1[5]) + (e1[6] + e1[7]));
            union { u32 u[4]; bf16x8 v; } pA0, pA1;
            pA0.u[0] = pk_trunc(e0[0], e0[1]);
            pA0.u[1] = pk_trunc(e0[2], e0[3]);
            pA0.u[2] = pk_trunc(e0[4], e0[5]);
            pA0.u[3] = pk_trunc(e0[6], e0[7]);
            pA1.u[0] = pk_trunc(e1[0], e1[1]);
            pA1.u[1] = pk_trunc(e1[2], e1[3]);
            pA1.u[2] = pk_trunc(e1[4], e1[5]);
            pA1.u[3] = pk_trunc(e1[6], e1[7]);

            O[qb][0] = __builtin_amdgcn_mfma_f32_16x16x32_bf16(pA0.v, vf[0][0], O[qb][0], 0, 0, 0);
            O[qb][1] = __builtin_amdgcn_mfma_f32_16x16x32_bf16(pA0.v, vf[0][1], O[qb][1], 0, 0, 0);
            O[qb][0] = __builtin_amdgcn_mfma_f32_16x16x32_bf16(pA1.v, vf[1][0], O[qb][0], 0, 0, 0);
            O[qb][1] = __builtin_amdgcn_mfma_f32_16x16x32_bf16(pA1.v, vf[1][1], O[qb][1], 0, 0, 0);
        }
    }

    // l: lane holds partial sum for query qb*16 + l16; sum the 4 quad copies.
    #pragma unroll
    for (int qb = 0; qb < 2; ++qb) {
        lp[qb] += __shfl_xor(lp[qb], 16);
        lp[qb] += __shfl_xor(lp[qb], 32);
    }

    // ---- combine the four key-quarters (pure addition) ----
    if (wave > 0) {
        float* cb = cbuf[wave - 1];
        #pragma unroll
        for (int qb = 0; qb < 2; ++qb)
            #pragma unroll
            for (int r = 0; r < 4; ++r) {
                const int row = qb * 16 + quad * 4 + r;
                cb[row * 33 + l16]      = O[qb][0][r];
                cb[row * 33 + 16 + l16] = O[qb][1][r];
                if (l16 == 0)
                    cb[row * 33 + 32] = __shfl(lp[qb], quad * 4 + r);
            }
    }
    __syncthreads();
    if (wave == 0) {
        #pragma unroll
        for (int qb = 0; qb < 2; ++qb)
            #pragma unroll
            for (int r = 0; r < 4; ++r) {
                const int row = qb * 16 + quad * 4 + r;
                float lq = __shfl(lp[qb], quad * 4 + r);
                float o0 = O[qb][0][r];
                float o1 = O[qb][1][r];
                #pragma unroll
                for (int s = 0; s < 3; ++s) {
                    const float* cb = cbuf[s];
                    o0 += cb[row * 33 + l16];
                    o1 += cb[row * 33 + 16 + l16];
                    lq += cb[row * 33 + 32];
                }
                const float inv = 1.0f / lq;
                const int q = q0 + row;
                u16* crow = ctx + ((size_t)(b * kS + q)) * kD + h * kDH;
                crow[l16]      = f2bf(o0 * inv);
                crow[16 + l16] = f2bf(o1 * inv);
            }
    }
}

// ---------------------------------------------------------------------------
// 7 dispatches: ln1 -> qkv -> attn -> proj(+res) -> ln2 -> ffn1(SiLU) ->
// ffn2(+res). Workspace (bytes):
//   [ 0M, 4M)  Qb   (bf16)  -- [0,8M) reused as h after attn
//   [ 4M, 8M)  Kb   (bf16)
//   [ 8M,12M)  Vp   (bf16, quad-interleaved)
//   [12M,16M)  ctx  (bf16)
//   [16M,20M)  y    (bf16, LN1 then LN2)
// ---------------------------------------------------------------------------
extern "C" void kernel_launch(void* const* d_in, const int* in_sizes, int n_in,
                              void* d_out, int out_size, void* d_ws, size_t ws_size,
                              hipStream_t stream)
{
    const float* x      = (const float*)d_in[0];
    const float* ln1_g  = (const float*)d_in[1];
    const float* ln1_b  = (const float*)d_in[2];
    const float* w_qkv  = (const float*)d_in[3];
    const float* b_qkv  = (const float*)d_in[4];
    const float* w_proj = (const float*)d_in[5];
    const float* b_proj = (const float*)d_in[6];
    const float* ln2_g  = (const float*)d_in[7];
    const float* ln2_b  = (const float*)d_in[8];
    const float* w1     = (const float*)d_in[9];
    const float* b1     = (const float*)d_in[10];
    const float* w2     = (const float*)d_in[11];
    const float* b2     = (const float*)d_in[12];
    float* out = (float*)d_out;

    char* ws = (char*)d_ws;
    u16* Qb  = (u16*)ws;
    u16* Kb  = (u16*)(ws + ((size_t)4  << 20));
    u16* Vp  = (u16*)(ws + ((size_t)8  << 20));
    u16* ctx = (u16*)(ws + ((size_t)12 << 20));
    u16* y   = (u16*)(ws + ((size_t)16 << 20));
    u16* h   = (u16*)ws;                     // aliases Qb/Kb (dead after attn)

    const dim3 blk(256);

    // 1) y = bf16(LN1(x))
    ln_kernel<<<dim3(kM / 4), blk, 0, stream>>>(x, ln1_g, ln1_b, y);
    // 2) Qb/Kb/Vp = bf16(y @ w_qkv.T + b_qkv), Q pre-scaled, V interleaved
    gemm_bf16<64, 2, false, 256><<<dim3(kM / 128, 12), blk, 0, stream>>>(
        y, w_qkv, b_qkv, nullptr, nullptr, Qb, Kb, Vp, 0);
    // 3) ctx = attention (bf16 out), in-register P, 4-way key split
    attn_kernel<<<dim3(kS / 32, kH, kB), blk, 0, stream>>>(Qb, Kb, Vp, ctx);
    // 4) out = x + ctx @ w_proj.T + b_proj   (fp32)
    gemm_bf16<32, 0, true, 256><<<dim3(kM / 128, kD / 32), blk, 0, stream>>>(
        ctx, w_proj, b_proj, x, out, nullptr, nullptr, nullptr, kD);
    // 5) y = bf16(LN2(out))
    ln_kernel<<<dim3(kM / 4), blk, 0, stream>>>(out, ln2_g, ln2_b, y);
    // 6) h = bf16(silu(y @ w1.T + b1))
    gemm_bf16<64, 1, false, 256><<<dim3(kM / 128, kDFF / 64), blk, 0, stream>>>(
        y, w1, b1, nullptr, nullptr, h, nullptr, nullptr, kDFF);
    // 7) out = out + h @ w2.T + b2   (fp32, K=512)
    gemm_bf16<32, 0, true, 512><<<dim3(kM / 128, kD / 32), blk, 0, stream>>>(
        h, w2, b2, out, out, nullptr, nullptr, nullptr, kD);
}